// Round 7
// baseline (375.338 us; speedup 1.0000x reference)
//
#include <hip/hip_runtime.h>
#include <cstdint>
#include <cstddef>

typedef __attribute__((ext_vector_type(8))) short bf16x8;
typedef __attribute__((ext_vector_type(4))) float f32x4;

__device__ __forceinline__ unsigned short f2bf(float f) {
  union { float f; uint32_t u; } v; v.f = f;
  uint32_t r = v.u + 0x7fffu + ((v.u >> 16) & 1u);
  return (unsigned short)(r >> 16);
}
__device__ __forceinline__ float bf2f(unsigned short u) {
  union { uint32_t u; float f; } v; v.u = ((uint32_t)u) << 16;
  return v.f;
}

__device__ __forceinline__ void glds16(const void* g, void* l) {
  __builtin_amdgcn_global_load_lds(
      (const __attribute__((address_space(1))) unsigned int*)g,
      (__attribute__((address_space(3))) unsigned int*)l, 16, 0, 0);
}

// Q/K/V/att per-head offsets (elements). Layout per head: [b][s][l][128].
// L = 64>>h, cumL = {0,64,96,112}, off = B*SEG*cumL*128 = 65536*cumL
__device__ __forceinline__ size_t head_off(int h) {
  return (size_t)65536 * ((h == 0) ? 0 : (h == 1) ? 64 : (h == 2) ? 96 : 112);
}

// ---------------- fp32 -> bf16 converts ----------------
__global__ void k_cvt(const float* __restrict__ src, unsigned short* __restrict__ dst, int n4) {
  int i = blockIdx.x * 256 + threadIdx.x;
  if (i < n4) {
    float4 f = ((const float4*)src)[i];
    ushort4 u;
    u.x = f2bf(f.x); u.y = f2bf(f.y); u.z = f2bf(f.z); u.w = f2bf(f.w);
    ((ushort4*)dst)[i] = u;
  }
}

// Concat per head: rows [0:128)=Wq, [128:256)=Wk, [256:384)=Wv  (row-major [j][e], e=1024)
__global__ void k_cvt_w(const float* __restrict__ Wq, const float* __restrict__ Wk,
                        const float* __restrict__ Wv, unsigned short* __restrict__ dst) {
  int row = blockIdx.x;              // h*384 + j, 1536 rows
  int h = row / 384, j = row % 384;
  const float* src = (j < 128) ? (Wq + (size_t)(h * 128 + j) * 1024)
                   : (j < 256) ? (Wk + (size_t)(h * 128 + j - 128) * 1024)
                               : (Wv + (size_t)(h * 128 + j - 256) * 1024);
  int e = threadIdx.x * 4;
  float4 f = *(const float4*)(src + e);
  ushort4 u;
  u.x = f2bf(f.x); u.y = f2bf(f.y); u.z = f2bf(f.z); u.w = f2bf(f.w);
  *(ushort4*)(dst + (size_t)row * 1024 + e) = u;
}

// ---------------- stage 1: QKV projection GEMM (global_load_lds + XCD swizzle) ----------------
// 1-D grid 1440 = 60 groups x {gy 0..2} x {slot 0..7}; same-gx triple lands on one XCD.
__global__ __launch_bounds__(256) void k_qkv(
    const unsigned short* __restrict__ xbf,
    const unsigned short* __restrict__ wbf,
    unsigned short* __restrict__ qws,
    unsigned short* __restrict__ kws,
    unsigned short* __restrict__ vws) {
  int i = blockIdx.x;
  int group = i / 24, jj = i - group * 24;
  int gy = jj >> 3, slot = jj & 7;
  int gx = group * 8 + slot;
  int h, base;
  if (gx < 256)      { h = 0; base = 0; }
  else if (gx < 384) { h = 1; base = 256; }
  else if (gx < 448) { h = 2; base = 384; }
  else               { h = 3; base = 448; }
  int L = 64 >> h, dil = 1 << h;
  int inner = gx - base;
  int b = inner >> (6 - h);
  int l = inner & (L - 1);
  const unsigned short* Abase = xbf + ((size_t)(b * 8192 + l * dil * 128)) * 1024;
  const unsigned short* Bbase = wbf + ((size_t)(h * 384 + gy * 128)) * 1024;

  __shared__ unsigned short As[128 * 64];
  __shared__ unsigned short Bs[128 * 64];

  int tid = threadIdx.x;
  int lane = tid & 63, wave = tid >> 6;
  int wm = wave >> 1, wn = wave & 1;
  int li = lane & 15, lk8 = (lane >> 4) << 3;

  int urow = tid >> 3;          // 0..31: row within a 32-row staging slab
  int uc8 = (tid & 7) << 3;     // col offset (elems)

  f32x4 acc[4][4] = {};

  for (int kc = 0; kc < 1024; kc += 64) {
    __syncthreads();                       // LDS free (prev MFMA reads done)
#pragma unroll
    for (int it = 0; it < 4; ++it) {
      int row = it * 32 + urow;
      glds16(Abase + (size_t)row * 1024 + kc + uc8, &As[it * 2048 + wave * 512]);
      glds16(Bbase + (size_t)row * 1024 + kc + uc8, &Bs[it * 2048 + wave * 512]);
    }
    __syncthreads();                       // drains vmcnt -> tiles ready
#pragma unroll
    for (int kk = 0; kk < 2; ++kk) {
      int k0 = kk * 32 + lk8;
      bf16x8 af[4], bfv[4];
#pragma unroll
      for (int mf = 0; mf < 4; ++mf)
        af[mf] = *(const bf16x8*)&As[(wm * 64 + mf * 16 + li) * 64 + k0];
#pragma unroll
      for (int nf = 0; nf < 4; ++nf)
        bfv[nf] = *(const bf16x8*)&Bs[(wn * 64 + nf * 16 + li) * 64 + k0];
#pragma unroll
      for (int mf = 0; mf < 4; ++mf)
#pragma unroll
        for (int nf = 0; nf < 4; ++nf)
          acc[mf][nf] = __builtin_amdgcn_mfma_f32_16x16x32_bf16(af[mf], bfv[nf], acc[mf][nf], 0, 0, 0);
    }
  }
  unsigned short* dst = ((gy == 0) ? qws : (gy == 1) ? kws : vws) + head_off(h);
  int ib = (lane >> 4) * 4;
#pragma unroll
  for (int mf = 0; mf < 4; ++mf) {
#pragma unroll
    for (int nf = 0; nf < 4; ++nf) {
#pragma unroll
      for (int rg = 0; rg < 4; ++rg) {
        int s = wm * 64 + mf * 16 + ib + rg;
        int j = wn * 64 + nf * 16 + li;
        dst[((size_t)((b * 128 + s) * L + l)) * 128 + j] = f2bf(acc[mf][nf][rg]);
      }
    }
  }
}

// ---------------- stage 2: MFMA dilated attention (unchanged) ----------------
__global__ __launch_bounds__(256) void k_attn(
    const unsigned short* __restrict__ qws,
    const unsigned short* __restrict__ kws,
    const unsigned short* __restrict__ vws,
    unsigned short* __restrict__ att) {
  int bx = blockIdx.x;
  int h, inst;
  if (bx < 512)      { h = 0; inst = bx; }
  else if (bx < 768) { h = 1; inst = bx - 512; }
  else if (bx < 896) { h = 2; inst = bx - 768; }
  else               { h = 3; inst = bx - 896; }
  int lgL = 6 - h;
  int L = 64 >> h;
  int Lm1 = L - 1;
  int bpb = 128 >> h;                     // blocks per batch
  int b = inst / bpb;
  int s0 = (inst % bpb) << h;
  size_t off0 = head_off(h) + ((size_t)(b * 128 + s0) * L) * 128;  // contiguous 64x128
  const unsigned short* Qg = qws + off0;
  const unsigned short* Kg = kws + off0;
  const unsigned short* Vg = vws + off0;
  unsigned short* Og = att + off0;

  __shared__ unsigned short PT[64][72];     // P^T[m][n]
  __shared__ unsigned short VtL[128][72];   // V^T[v][n]

  int tid = threadIdx.x;
  int lane = tid & 63, w = tid >> 6;
  int li = lane & 15, q = lane >> 4;
  int lk8 = q << 3;

#pragma unroll
  for (int c = 0; c < 4; ++c) {
    int u = tid + c * 256;          // 1024 units of 8 elems
    int n = u & 63, vblk = u >> 6;
    bf16x8 ve = *(const bf16x8*)(Vg + n * 128 + vblk * 8);
#pragma unroll
    for (int j = 0; j < 8; ++j)
      VtL[vblk * 8 + j][n] = (unsigned short)ve[j];
  }

  f32x4 sacc[4] = {};
  int nrow = 16 * w + li;
  for (int kc = 0; kc < 4; ++kc) {
    int d0 = kc * 32 + lk8;
    bf16x8 af = *(const bf16x8*)(Kg + nrow * 128 + d0);
#pragma unroll
    for (int mt = 0; mt < 4; ++mt) {
      bf16x8 bfq = *(const bf16x8*)(Qg + (mt * 16 + li) * 128 + d0);
      sacc[mt] = __builtin_amdgcn_mfma_f32_16x16x32_bf16(af, bfq, sacc[mt], 0, 0, 0);
    }
  }

  float sv[4][4];
#pragma unroll
  for (int mt = 0; mt < 4; ++mt)
#pragma unroll
    for (int r = 0; r < 4; ++r) {
      int n = 16 * w + 4 * q + r;
      int m = mt * 16 + li;
      bool valid = ((m >> lgL) == (n >> lgL)) && ((m & Lm1) <= (n & Lm1));
      sv[mt][r] = valid ? sacc[mt][r] * 0.08838834764831845f : -1e30f;
    }
  float inv[4];
#pragma unroll
  for (int r = 0; r < 4; ++r) {
    float m0 = fmaxf(fmaxf(sv[0][r], sv[1][r]), fmaxf(sv[2][r], sv[3][r]));
#pragma unroll
    for (int d = 1; d < 16; d <<= 1)
      m0 = fmaxf(m0, __shfl_xor(m0, d, 64));
    float s0 = 0.f;
#pragma unroll
    for (int mt = 0; mt < 4; ++mt) {
      sv[mt][r] = __expf(sv[mt][r] - m0);
      s0 += sv[mt][r];
    }
#pragma unroll
    for (int d = 1; d < 16; d <<= 1)
      s0 += __shfl_xor(s0, d, 64);
    inv[r] = 1.f / s0;
  }

#pragma unroll
  for (int mt = 0; mt < 4; ++mt) {
    ushort4 pk;
    pk.x = f2bf(sv[mt][0] * inv[0]);
    pk.y = f2bf(sv[mt][1] * inv[1]);
    pk.z = f2bf(sv[mt][2] * inv[2]);
    pk.w = f2bf(sv[mt][3] * inv[3]);
    *(ushort4*)&PT[mt * 16 + li][16 * w + 4 * q] = pk;
  }
  __syncthreads();

  f32x4 oacc[8] = {};
#pragma unroll
  for (int ks = 0; ks < 2; ++ks) {
    int n0 = ks * 32 + lk8;
    bf16x8 af = *(const bf16x8*)&PT[16 * w + li][n0];
#pragma unroll
    for (int vt = 0; vt < 8; ++vt) {
      bf16x8 bfv = *(const bf16x8*)&VtL[vt * 16 + li][n0];
      oacc[vt] = __builtin_amdgcn_mfma_f32_16x16x32_bf16(af, bfv, oacc[vt], 0, 0, 0);
    }
  }
#pragma unroll
  for (int vt = 0; vt < 8; ++vt) {
#pragma unroll
    for (int r = 0; r < 4; ++r) {
      int m = 16 * w + 4 * q + r;
      int v = vt * 16 + li;
      Og[m * 128 + v] = f2bf(oacc[vt][r]);
    }
  }
}

// ---------------- stage 3: gather + output projection GEMM (global_load_lds) ----------------
__global__ __launch_bounds__(256) void k_out(
    const unsigned short* __restrict__ att,
    const unsigned short* __restrict__ wout,
    const float* __restrict__ bout,
    float* __restrict__ out) {
  int mt = blockIdx.x, nt = blockIdx.y;
  int row0 = mt * 128;

  __shared__ unsigned short As[128 * 64];
  __shared__ unsigned short Bs[128 * 64];

  int tid = threadIdx.x;
  int lane = tid & 63, wave = tid >> 6;
  int wm = wave >> 1, wn = wave & 1;
  int li = lane & 15, lk8 = (lane >> 4) << 3;

  int urow = tid >> 3;
  int uc8 = (tid & 7) << 3;
  const bf16x8 ZV = {0, 0, 0, 0, 0, 0, 0, 0};

  f32x4 acc[4][4] = {};

  for (int kc = 0; kc < 512; kc += 64) {
    int hd = kc >> 7;                 // head uniform per kc chunk
    int dil = 1 << hd, Lh = 64 >> hd, v0 = kc & 127;
    __syncthreads();
#pragma unroll
    for (int it = 0; it < 4; ++it) {
      int row = it * 32 + urow;
      glds16(wout + (size_t)(nt * 128 + row) * 512 + kc + uc8, &Bs[it * 2048 + wave * 512]);
    }
#pragma unroll
    for (int it = 0; it < 4; ++it) {
      int row = it * 32 + urow;
      int rg = row0 + row;
      int b = rg >> 13, t = rg & 8191;
      if ((t & (dil - 1)) == 0) {
        int j2 = t >> hd;
        int s = j2 >> (6 - hd), l2 = j2 & (Lh - 1);
        glds16(att + head_off(hd) + ((size_t)((b * 128 + s) * Lh + l2)) * 128 + v0 + uc8,
               &As[it * 2048 + wave * 512]);
      } else {
        *(bf16x8*)&As[it * 2048 + wave * 512 + lane * 8] = ZV;
      }
    }
    __syncthreads();
#pragma unroll
    for (int kk = 0; kk < 2; ++kk) {
      int k0 = kk * 32 + lk8;
      bf16x8 af[4], bfv[4];
#pragma unroll
      for (int mf = 0; mf < 4; ++mf)
        af[mf] = *(const bf16x8*)&As[(wm * 64 + mf * 16 + li) * 64 + k0];
#pragma unroll
      for (int nf = 0; nf < 4; ++nf)
        bfv[nf] = *(const bf16x8*)&Bs[(wn * 64 + nf * 16 + li) * 64 + k0];
#pragma unroll
      for (int mf = 0; mf < 4; ++mf)
#pragma unroll
        for (int nf = 0; nf < 4; ++nf)
          acc[mf][nf] = __builtin_amdgcn_mfma_f32_16x16x32_bf16(af[mf], bfv[nf], acc[mf][nf], 0, 0, 0);
    }
  }
  int ib = (lane >> 4) * 4;
#pragma unroll
  for (int mf = 0; mf < 4; ++mf) {
#pragma unroll
    for (int nf = 0; nf < 4; ++nf) {
      int col = nt * 128 + wn * 64 + nf * 16 + li;
      float bo = bout[col];
#pragma unroll
      for (int rg = 0; rg < 4; ++rg) {
        int r = row0 + wm * 64 + mf * 16 + ib + rg;
        out[(size_t)r * 1024 + col] = acc[mf][nf][rg] + bo;
      }
    }
  }
}

extern "C" void kernel_launch(void* const* d_in, const int* in_sizes, int n_in,
                              void* d_out, int out_size, void* d_ws, size_t ws_size,
                              hipStream_t stream) {
  const float* x  = (const float*)d_in[0];
  const float* Wk = (const float*)d_in[1];
  const float* Wq = (const float*)d_in[2];
  const float* Wv = (const float*)d_in[3];
  const float* Wo = (const float*)d_in[4];
  const float* bo = (const float*)d_in[5];
  float* out = (float*)d_out;
  char* ws = (char*)d_ws;
  unsigned short* xbf  = (unsigned short*)(ws);
  unsigned short* wbf  = (unsigned short*)(ws + 67108864);
  unsigned short* wobf = (unsigned short*)(ws + 70254592);
  unsigned short* qws  = (unsigned short*)(ws + 71303168);
  unsigned short* kws  = (unsigned short*)(ws + 87031808);
  unsigned short* vws  = (unsigned short*)(ws + 102760448);
  unsigned short* attw = (unsigned short*)(ws + 118489088);

  k_cvt<<<dim3(32768), dim3(256), 0, stream>>>(x, xbf, 8388608);
  k_cvt_w<<<dim3(1536), dim3(256), 0, stream>>>(Wq, Wk, Wv, wbf);
  k_cvt<<<dim3(512), dim3(256), 0, stream>>>(Wo, wobf, 131072);
  k_qkv<<<dim3(1440), dim3(256), 0, stream>>>(xbf, wbf, qws, kws, vws);
  k_attn<<<dim3(960), dim3(256), 0, stream>>>(qws, kws, vws, attw);
  k_out<<<dim3(256, 8), dim3(256), 0, stream>>>(attw, wobf, bo, out);
}